// Round 1
// baseline (1198.291 us; speedup 1.0000x reference)
//
#include <hip/hip_runtime.h>

static constexpr int BATCH = 131072;
static constexpr int SENSN = 61;
static constexpr int HIDN  = 64;
static constexpr int NSTEP = 10;

// tanh(x) = 1 - 2/(exp(2x)+1); exact saturation at +-inf, ~1e-7 abs error.
__device__ __forceinline__ float fast_tanh(float x) {
    float e = __expf(2.0f * x);                  // v_mul + v_exp_f32
    float r = __builtin_amdgcn_rcpf(e + 1.0f);   // v_add + v_rcp_f32
    return fmaf(-2.0f, r, 1.0f);
}

__global__ void __launch_bounds__(256, 2)
node_kernel(const float* __restrict__ pad0,
            const float* __restrict__ sens,
            const float* __restrict__ W1,
            const float* __restrict__ b1v,
            const float* __restrict__ W2,
            const float* __restrict__ b2v,
            const float* __restrict__ W3,
            const float* __restrict__ b3v,
            const float* __restrict__ scale_p,
            float* __restrict__ out)
{
    const int b = blockIdx.x * 256 + threadIdx.x;

    // ---- one-time: S[j] = b1[j] + sensory[b,:] @ W1[3:64,:]  (t-eval invariant) ----
    float S[HIDN];
#pragma unroll
    for (int j = 0; j < HIDN; ++j) S[j] = b1v[j];
    {
        const float* __restrict__ srow = sens + (long)b * SENSN;
#pragma unroll 1
        for (int s = 0; s < SENSN; ++s) {
            const float xv = srow[s];
            const float* __restrict__ w = W1 + (3 + s) * HIDN;  // uniform addr -> s_load
#pragma unroll
            for (int j = 0; j < HIDN; ++j) S[j] = fmaf(xv, w[j], S[j]);
        }
    }

    float y0 = pad0[b * 3 + 0];
    float y1 = pad0[b * 3 + 1];
    float y2 = pad0[b * 3 + 2];
    const float scale = *scale_p;
    const float h = 0.1f;

    // k1..k5 in registers (k6 folded into the final combine)
    float k00=0,k01=0,k02=0, k10=0,k11=0,k12=0, k20=0,k21=0,k22=0,
          k30=0,k31=0,k32=0, k40=0,k41=0,k42=0;

#pragma unroll 1
    for (int step = 0; step < NSTEP; ++step) {
        const float t0 = (float)step * h;
#pragma unroll 1
        for (int st = 0; st < 6; ++st) {   // runtime loop: one copy of the MLP body
            float tt = t0, v0 = y0, v1 = y1, v2 = y2;
            switch (st) {                  // wave-uniform branch
            case 0: break;
            case 1: {
                const float a21 = (float)(1.0/5.0);
                v0 = fmaf(h, a21*k00, y0);
                v1 = fmaf(h, a21*k01, y1);
                v2 = fmaf(h, a21*k02, y2);
                tt = t0 + 0.2f*h;
            } break;
            case 2: {
                const float a31 = (float)(3.0/40.0), a32 = (float)(9.0/40.0);
                v0 = fmaf(h, a31*k00 + a32*k10, y0);
                v1 = fmaf(h, a31*k01 + a32*k11, y1);
                v2 = fmaf(h, a31*k02 + a32*k12, y2);
                tt = t0 + 0.3f*h;
            } break;
            case 3: {
                const float a41 = (float)(44.0/45.0), a42 = (float)(-56.0/15.0),
                            a43 = (float)(32.0/9.0);
                v0 = fmaf(h, a41*k00 + a42*k10 + a43*k20, y0);
                v1 = fmaf(h, a41*k01 + a42*k11 + a43*k21, y1);
                v2 = fmaf(h, a41*k02 + a42*k12 + a43*k22, y2);
                tt = t0 + 0.8f*h;
            } break;
            case 4: {
                const float a51 = (float)(19372.0/6561.0), a52 = (float)(-25360.0/2187.0),
                            a53 = (float)(64448.0/6561.0), a54 = (float)(-212.0/729.0);
                v0 = fmaf(h, a51*k00 + a52*k10 + a53*k20 + a54*k30, y0);
                v1 = fmaf(h, a51*k01 + a52*k11 + a53*k21 + a54*k31, y1);
                v2 = fmaf(h, a51*k02 + a52*k12 + a53*k22 + a54*k32, y2);
                tt = t0 + (float)(8.0/9.0)*h;
            } break;
            default: {
                const float a61 = (float)(9017.0/3168.0), a62 = (float)(-355.0/33.0),
                            a63 = (float)(46732.0/5247.0), a64 = (float)(49.0/176.0),
                            a65 = (float)(-5103.0/18656.0);
                v0 = fmaf(h, a61*k00 + a62*k10 + a63*k20 + a64*k30 + a65*k40, y0);
                v1 = fmaf(h, a61*k01 + a62*k11 + a63*k21 + a64*k31 + a65*k41, y1);
                v2 = fmaf(h, a61*k02 + a62*k12 + a63*k22 + a64*k32 + a65*k42, y2);
                tt = t0 + h;
            } break;
            }

            // ---- f(tt, v): layer 1 (rank-3 y-update + rank-1 t-update on S) ----
            float a[HIDN];
#pragma unroll
            for (int j = 0; j < HIDN; ++j) {
                float z = S[j];
                z = fmaf(v0, W1[0*HIDN + j], z);
                z = fmaf(v1, W1[1*HIDN + j], z);
                z = fmaf(v2, W1[2*HIDN + j], z);
                z = fmaf(tt, W1[64*HIDN + j], z);
                a[j] = fast_tanh(z);
            }
            // ---- layer 2: zz = a @ W2 + b2 (i-outer so W2 rows are contiguous s_loads)
            float zz[HIDN];
#pragma unroll
            for (int j = 0; j < HIDN; ++j) zz[j] = b2v[j];
#pragma unroll 4
            for (int i = 0; i < HIDN; ++i) {
                const float ai = a[i];
                const float* __restrict__ w = W2 + i * HIDN;
#pragma unroll
                for (int j = 0; j < HIDN; ++j) zz[j] = fmaf(ai, w[j], zz[j]);
            }
            // ---- layer 3: 64 -> 3, fused with tanh(zz) ----
            float s0 = b3v[0], s1 = b3v[1], s2 = b3v[2];
#pragma unroll
            for (int i = 0; i < HIDN; ++i) {
                const float t2 = fast_tanh(zz[i]);
                s0 = fmaf(t2, W3[i*3 + 0], s0);
                s1 = fmaf(t2, W3[i*3 + 1], s1);
                s2 = fmaf(t2, W3[i*3 + 2], s2);
            }
            const float r0 = fast_tanh(s0) * scale;
            const float r1 = fast_tanh(s1) * scale;
            const float r2 = fast_tanh(s2) * scale;

            switch (st) {
            case 0: k00=r0; k01=r1; k02=r2; break;
            case 1: k10=r0; k11=r1; k12=r2; break;
            case 2: k20=r0; k21=r1; k22=r2; break;
            case 3: k30=r0; k31=r1; k32=r2; break;
            case 4: k40=r0; k41=r1; k42=r2; break;
            default: {   // st==5: r is k6 — final 5th-order combine
                const float c1 = (float)(35.0/384.0),  c3 = (float)(500.0/1113.0),
                            c4 = (float)(125.0/192.0), c5 = (float)(-2187.0/6784.0),
                            c6 = (float)(11.0/84.0);
                y0 = fmaf(h, c1*k00 + c3*k20 + c4*k30 + c5*k40 + c6*r0, y0);
                y1 = fmaf(h, c1*k01 + c3*k21 + c4*k31 + c5*k41 + c6*r1, y1);
                y2 = fmaf(h, c1*k02 + c3*k22 + c4*k32 + c5*k42 + c6*r2, y2);
            } break;
            }
        }
    }

    out[b*3 + 0] = y0;
    out[b*3 + 1] = y1;
    out[b*3 + 2] = y2;
}

extern "C" void kernel_launch(void* const* d_in, const int* in_sizes, int n_in,
                              void* d_out, int out_size, void* d_ws, size_t ws_size,
                              hipStream_t stream) {
    const float* pad0 = (const float*)d_in[0];
    const float* sens = (const float*)d_in[1];
    const float* W1   = (const float*)d_in[2];
    const float* b1v  = (const float*)d_in[3];
    const float* W2   = (const float*)d_in[4];
    const float* b2v  = (const float*)d_in[5];
    const float* W3   = (const float*)d_in[6];
    const float* b3v  = (const float*)d_in[7];
    const float* sc   = (const float*)d_in[8];
    float* out = (float*)d_out;

    dim3 grid(BATCH / 256), block(256);
    hipLaunchKernelGGL(node_kernel, grid, block, 0, stream,
                       pad0, sens, W1, b1v, W2, b2v, W3, b3v, sc, out);
}